// Round 27
// baseline (29.182 us; speedup 1.0000x reference)
//
#include <hip/hip_runtime.h>

#define D 256
#define W8 2048

// ws float offsets: BPART (4x256 f32) at 0; T^T bf16 [256 d][136 k] at 1024
#define BPART_OFF 0
#define TBT_OFF   1024
#define KS 136     // padded K stride (halfwords); K used = 102 (F zero-covers the rest)

typedef float f32x4 __attribute__((ext_vector_type(4)));
typedef short short8 __attribute__((ext_vector_type(8)));   // 8 bf16 = 4 VGPR

__device__ __forceinline__ ushort bf16rne(float v) {
    const unsigned x = __float_as_uint(v);
    return (ushort)((x + 0x7fffu + ((x >> 16) & 1u)) >> 16);
}

// -------- fuse v5 (R17 core) — emits bf16 T^T rows [d][k] + f32 bias partials

__global__ __launch_bounds__(256) void fuse5_kernel(
    const float* __restrict__ combine_W,
    const float* __restrict__ card_t, const float* __restrict__ hero_t,
    const float* __restrict__ act_t,  const float* __restrict__ nump_t,
    const float* __restrict__ scalar_W, const float* __restrict__ scalar_b,
    const float* __restrict__ blind_W,  const float* __restrict__ blind_b,
    const float* __restrict__ bet_W,    const float* __restrict__ bet_b,
    const float* __restrict__ action_W, const float* __restrict__ action_b,
    float* __restrict__ ws)
{
    __shared__ float vsh[D];
    __shared__ float Wl[D * 33];

    const int job = blockIdx.x;   // 0..105
    const int tid = threadIdx.x;

    int wblk;
    float scale = 1.0f;
    int kind, orow;

    if (job < 81) {               // T rows k=0..80 (card pre-scaled 1/7)
        kind = 0; orow = job;
        const float* src;
        if (job < 53)      { src = card_t + job * D;        wblk = 0; scale = 1.0f / 7.0f; }
        else if (job < 62) { src = hero_t + (job - 53) * D; wblk = 1; }
        else if (job < 71) { src = act_t  + (job - 62) * D; wblk = 2; }
        else               { src = nump_t + (job - 71) * D; wblk = 6; }
        vsh[tid] = src[tid];
    } else if (job < 102) {       // T rows k=81..101 (section weight columns)
        kind = 1; orow = job - 81;
        const float* secW; int nk, k;
        if (orow < 2)       { secW = scalar_W; nk = 2; k = orow;      wblk = 3; }
        else if (orow < 11) { secW = bet_W;    nk = 9; k = orow - 2;  wblk = 4; }
        else if (orow < 19) { secW = action_W; nk = 8; k = orow - 11; wblk = 5; }
        else                { secW = blind_W;  nk = 2; k = orow - 19; wblk = 7; }
        vsh[tid] = secW[tid * nk + k];
    } else {                      // bias partials (f32; summed in gemm epilogue)
        kind = 2; orow = job - 102;
        const float* secB;
        switch (orow) {
            case 0:  secB = scalar_b; wblk = 3; break;
            case 1:  secB = bet_b;    wblk = 4; break;
            case 2:  secB = action_b; wblk = 5; break;
            default: secB = blind_b;  wblk = 7; break;
        }
        vsh[tid] = secB[tid];
    }

    const float* Wbase = combine_W + wblk * D;
    float acc = 0.f;

    for (int t = 0; t < 8; ++t) {
        const int k0 = t * 32;
        __syncthreads();
#pragma unroll
        for (int i = 0; i < 8; ++i) {
            const int fidx = tid + i * 256;
            const int dd = fidx >> 3;
            const int kq = (fidx & 7) * 4;
            const float4 w = *(const float4*)(Wbase + (size_t)dd * W8 + k0 + kq);
            float* p = Wl + dd * 33 + kq;
            p[0] = w.x; p[1] = w.y; p[2] = w.z; p[3] = w.w;
        }
        __syncthreads();
        const float* wrow = Wl + tid * 33;
#pragma unroll
        for (int kk = 0; kk < 32; kk += 4) {
            const float4 vv = *(const float4*)(vsh + k0 + kk);
            acc += wrow[kk]     * vv.x + wrow[kk + 1] * vv.y
                 + wrow[kk + 2] * vv.z + wrow[kk + 3] * vv.w;
        }
    }

    ushort* tbT = (ushort*)(ws + TBT_OFF);
    float*  bpl = ws + BPART_OFF;
    if (kind == 0)      tbT[(size_t)tid * KS + orow]      = bf16rne(acc * scale);
    else if (kind == 1) tbT[(size_t)tid * KS + 81 + orow] = bf16rne(acc);
    else                bpl[orow * D + tid] = acc;
}

// -------- GEMM: swapped-operand MFMA, 2 tiles/block (R26) -------------------
// R27 single-variable experiment: PLAIN stores instead of nontemporal.
// NT bypasses L2 and drains to HBM at segment granularity (~0.8-1.9 TB/s
// observed on every store-heavy dispatch since R5); 32MB at that rate ~= the
// unexplained ~20us residual. Plain stores land in L2 (out ~= aggregate L2,
// L3 absorbs) and write back off the critical path.

#define GEMM_THREADS 256

struct Feat {
    int   c[7], ho, ao, no;
    float fs0, fs1, fb[9], fa[8], fl0, fl1, m;
};

__device__ __forceinline__ void preload(
    int q, int tok, int ok,
    const int* __restrict__ cards,  const int* __restrict__ hero,
    const int* __restrict__ acting, const int* __restrict__ nump,
    const float* __restrict__ scalars, const float* __restrict__ blinds,
    const float* __restrict__ bets,    const float* __restrict__ action,
    const float* __restrict__ mask, Feat& f)
{
    if (!ok) { f.m = 0.f; return; }
    if (q == 0) {
        const int* cp = cards + (size_t)tok * 7;
#pragma unroll
        for (int j = 0; j < 7; ++j) f.c[j] = cp[j];
        f.ho = hero[tok]; f.ao = acting[tok]; f.no = nump[tok];
        f.m = mask[tok];
    } else if (q == 1) {
        const float2 s = *(const float2*)(scalars + (size_t)tok * 2);
        f.fs0 = s.x; f.fs1 = s.y;
        const float* fb = bets + (size_t)tok * 9;
#pragma unroll
        for (int k = 0; k < 9; ++k) f.fb[k] = fb[k];
    } else if (q == 2) {
        const float* fa = action + (size_t)tok * 8;
#pragma unroll
        for (int k = 0; k < 8; ++k) f.fa[k] = fa[k];
        const float2 l = *(const float2*)(blinds + (size_t)tok * 2);
        f.fl0 = l.x; f.fl1 = l.y;
    }
}

__device__ __forceinline__ void writeF(int q, int t, int ok, const Feat& f,
                                       ushort* __restrict__ Fl, float* __restrict__ msk)
{
    ushort* Fr = Fl + t * KS;
    if (q == 0) {
        if (ok) {
            int cnt[7];
#pragma unroll
            for (int j = 0; j < 7; ++j) {
                int n = 1;
#pragma unroll
                for (int i = 0; i < 7; ++i)
                    if (i != j) n += (f.c[i] == f.c[j]) ? 1 : 0;
                cnt[j] = n;
            }
#pragma unroll
            for (int j = 0; j < 7; ++j)
                Fr[f.c[j]] = bf16rne((float)cnt[j]);   // exact for cnt<=7
            Fr[53 + f.ho] = 0x3F80;
            Fr[62 + f.ao] = 0x3F80;
            Fr[71 + f.no] = 0x3F80;
        }
        msk[t] = f.m;
    } else if (q == 1 && ok) {
        Fr[81] = bf16rne(f.fs0); Fr[82] = bf16rne(f.fs1);
#pragma unroll
        for (int k = 0; k < 9; ++k) Fr[83 + k] = bf16rne(f.fb[k]);
    } else if (q == 2 && ok) {
#pragma unroll
        for (int k = 0; k < 8; ++k) Fr[92 + k] = bf16rne(f.fa[k]);
        Fr[100] = bf16rne(f.fl0); Fr[101] = bf16rne(f.fl1);
    }
}

__device__ __forceinline__ void mfma_tile(
    const ushort* __restrict__ Tl, const ushort* __restrict__ Fl,
    const float* __restrict__ msk, const float* __restrict__ bsh,
    int tok0, int h, int w, int lr, int lg,
    float* __restrict__ out, int ntok)
{
    f32x4 acc[8];
#pragma unroll
    for (int mt = 0; mt < 8; ++mt) acc[mt] = (f32x4){0.f, 0.f, 0.f, 0.f};

#pragma unroll
    for (int kt = 0; kt < 4; ++kt) {
        const short8 b = *(const short8*)(Fl + (w * 16 + lr) * KS + kt * 32 + lg * 8);
#pragma unroll
        for (int mt = 0; mt < 8; ++mt) {
            const short8 a = *(const short8*)(Tl + (mt * 16 + lr) * KS + kt * 32 + lg * 8);
            acc[mt] = __builtin_amdgcn_mfma_f32_16x16x32_bf16(a, b, acc[mt], 0, 0, 0);
        }
    }

    const int tok = tok0 + w * 16 + lr;
    if (tok < ntok) {
        const float m = msk[w * 16 + lr];
#pragma unroll
        for (int mt = 0; mt < 8; ++mt) {
            const int c = mt * 16 + lg * 4;
            const float4 bb = *(const float4*)(bsh + c);
            float4 o;
            o.x = (acc[mt][0] + bb.x) * m;
            o.y = (acc[mt][1] + bb.y) * m;
            o.z = (acc[mt][2] + bb.z) * m;
            o.w = (acc[mt][3] + bb.w) * m;
            *(float4*)(out + (size_t)tok * D + h * 128 + c) = o;   // PLAIN store (R27)
        }
    }
}

__global__ __launch_bounds__(GEMM_THREADS) void gemm_kernel(
    const int* __restrict__ cards,  const int* __restrict__ hero,
    const int* __restrict__ acting, const int* __restrict__ nump,
    const float* __restrict__ scalars, const float* __restrict__ blinds,
    const float* __restrict__ bets,    const float* __restrict__ action,
    const float* __restrict__ mask,    const float* __restrict__ combine_b,
    const float* __restrict__ ws, float* __restrict__ out, int ntok, int ntiles)
{
    __shared__ __align__(16) ushort Tl[128 * KS];  // 34816 B
    __shared__ __align__(16) ushort Fl[64 * KS];   // 17408 B
    __shared__ float msk[64];
    __shared__ float bsh[128];

    const int tid  = threadIdx.x;
    const int h    = blockIdx.x & 1;
    const int tileA = (blockIdx.x >> 1) * 2;
    const int tileB = tileA + 1;
    const int tokA = tileA * 64;
    const int tokB = tileB * 64;

    const int q = tid >> 6;
    const int t = tid & 63;

    // phase 0: issue T-stage + F-zero + bias; preload tile-A features (regs)
    {
        const float4* src = (const float4*)((const ushort*)(ws + TBT_OFF) + (size_t)h * 128 * KS);
        float4* dst = (float4*)Tl;
        for (int i = tid; i < 128 * 17; i += GEMM_THREADS) dst[i] = src[i];
        uint* fz = (uint*)Fl;
        for (int i = tid; i < 64 * KS / 2; i += GEMM_THREADS) fz[i] = 0;
        if (tid < 128) {
            const int c = h * 128 + tid;
            bsh[tid] = combine_b[c]
                + ws[BPART_OFF + 0 * D + c] + ws[BPART_OFF + 1 * D + c]
                + ws[BPART_OFF + 2 * D + c] + ws[BPART_OFF + 3 * D + c];
        }
    }
    Feat fA;
    preload(q, tokA + t, tokA + t < ntok, cards, hero, acting, nump,
            scalars, blinds, bets, action, mask, fA);
    __syncthreads();

    // phase 1: write F(A)
    writeF(q, t, tokA + t < ntok, fA, Fl, msk);
    __syncthreads();

    // phase 2: MFMA + store tile A; preload tile-B features
    const int w  = tid >> 6;
    const int l  = tid & 63;
    const int lr = l & 15;
    const int lg = l >> 4;
    mfma_tile(Tl, Fl, msk, bsh, tokA, h, w, lr, lg, out, ntok);

    const int haveB = (tileB < ntiles);
    Feat fB;
    preload(q, tokB + t, haveB && (tokB + t < ntok), cards, hero, acting, nump,
            scalars, blinds, bets, action, mask, fB);
    __syncthreads();   // all Fl reads of tile A complete

    if (haveB) {
        // phase 3: q0 zeroes its stale tile-A slots, then write F(B)
        if (q == 0 && tokA + t < ntok) {
            ushort* Fr = Fl + t * KS;
#pragma unroll
            for (int j = 0; j < 7; ++j) Fr[fA.c[j]] = 0;
            Fr[53 + fA.ho] = 0; Fr[62 + fA.ao] = 0; Fr[71 + fA.no] = 0;
        }
        if (tokB + t >= ntok) {
            ushort* Fr = Fl + t * KS;
            if (q == 1) { for (int k = 81; k < 92; ++k) Fr[k] = 0; }
            if (q == 2) { for (int k = 92; k < 102; ++k) Fr[k] = 0; }
        }
        writeF(q, t, tokB + t < ntok, fB, Fl, msk);
        __syncthreads();

        // phase 4: MFMA + store tile B
        mfma_tile(Tl, Fl, msk, bsh, tokB, h, w, lr, lg, out, ntok);
    }
}

extern "C" void kernel_launch(void* const* d_in, const int* in_sizes, int n_in,
                              void* d_out, int out_size, void* d_ws, size_t ws_size,
                              hipStream_t stream) {
    const int*   cards    = (const int*)d_in[0];
    const int*   hero     = (const int*)d_in[1];
    const int*   acting   = (const int*)d_in[2];
    const int*   nump     = (const int*)d_in[3];
    const float* scalars  = (const float*)d_in[4];
    const float* blinds   = (const float*)d_in[5];
    const float* bets     = (const float*)d_in[6];
    const float* action   = (const float*)d_in[7];
    const float* mask     = (const float*)d_in[8];
    const float* card_t   = (const float*)d_in[9];
    const float* hero_t   = (const float*)d_in[10];
    const float* act_t    = (const float*)d_in[11];
    const float* nump_t   = (const float*)d_in[12];
    const float* scalar_W = (const float*)d_in[13];
    const float* scalar_b = (const float*)d_in[14];
    const float* blind_W  = (const float*)d_in[15];
    const float* blind_b  = (const float*)d_in[16];
    const float* bet_W    = (const float*)d_in[17];
    const float* bet_b    = (const float*)d_in[18];
    const float* action_W = (const float*)d_in[19];
    const float* action_b = (const float*)d_in[20];
    const float* combine_W= (const float*)d_in[21];
    const float* combine_b= (const float*)d_in[22];

    float* ws  = (float*)d_ws;
    float* out = (float*)d_out;
    const int ntok = in_sizes[1];  // B*S

    const int ntiles = (ntok + 63) / 64;
    const int npairs = (ntiles + 1) / 2;

    hipLaunchKernelGGL(fuse5_kernel, dim3(106), dim3(256), 0, stream,
                       combine_W, card_t, hero_t, act_t, nump_t,
                       scalar_W, scalar_b, blind_W, blind_b, bet_W, bet_b,
                       action_W, action_b, ws);
    hipLaunchKernelGGL(gemm_kernel, dim3(npairs * 2), dim3(GEMM_THREADS), 0, stream,
                       cards, hero, acting, nump, scalars, blinds, bets, action, mask,
                       combine_b, ws, out, ntok, ntiles);
}

// Round 28
// 27.972 us; speedup vs baseline: 1.0433x; 1.0433x over previous
//
#include <hip/hip_runtime.h>

#define D 256
#define W8 2048

// ws float offsets: BPART (4x256 f32) at 0; T^T bf16 [256 d][136 k] at 1024
#define BPART_OFF 0
#define TBT_OFF   1024
#define KS 136     // padded K stride (halfwords); K used = 102 (F zero-covers the rest)

typedef float nf4  __attribute__((ext_vector_type(4)));
typedef float f32x4 __attribute__((ext_vector_type(4)));
typedef short short8 __attribute__((ext_vector_type(8)));   // 8 bf16 = 4 VGPR

__device__ __forceinline__ ushort bf16rne(float v) {
    const unsigned x = __float_as_uint(v);
    return (ushort)((x + 0x7fffu + ((x >> 16) & 1u)) >> 16);
}

// -------- fuse v5 (R17 core) — emits bf16 T^T rows [d][k] + f32 bias partials

__global__ __launch_bounds__(256) void fuse5_kernel(
    const float* __restrict__ combine_W,
    const float* __restrict__ card_t, const float* __restrict__ hero_t,
    const float* __restrict__ act_t,  const float* __restrict__ nump_t,
    const float* __restrict__ scalar_W, const float* __restrict__ scalar_b,
    const float* __restrict__ blind_W,  const float* __restrict__ blind_b,
    const float* __restrict__ bet_W,    const float* __restrict__ bet_b,
    const float* __restrict__ action_W, const float* __restrict__ action_b,
    float* __restrict__ ws)
{
    __shared__ float vsh[D];
    __shared__ float Wl[D * 33];

    const int job = blockIdx.x;   // 0..105
    const int tid = threadIdx.x;

    int wblk;
    float scale = 1.0f;
    int kind, orow;

    if (job < 81) {               // T rows k=0..80 (card pre-scaled 1/7)
        kind = 0; orow = job;
        const float* src;
        if (job < 53)      { src = card_t + job * D;        wblk = 0; scale = 1.0f / 7.0f; }
        else if (job < 62) { src = hero_t + (job - 53) * D; wblk = 1; }
        else if (job < 71) { src = act_t  + (job - 62) * D; wblk = 2; }
        else               { src = nump_t + (job - 71) * D; wblk = 6; }
        vsh[tid] = src[tid];
    } else if (job < 102) {       // T rows k=81..101 (section weight columns)
        kind = 1; orow = job - 81;
        const float* secW; int nk, k;
        if (orow < 2)       { secW = scalar_W; nk = 2; k = orow;      wblk = 3; }
        else if (orow < 11) { secW = bet_W;    nk = 9; k = orow - 2;  wblk = 4; }
        else if (orow < 19) { secW = action_W; nk = 8; k = orow - 11; wblk = 5; }
        else                { secW = blind_W;  nk = 2; k = orow - 19; wblk = 7; }
        vsh[tid] = secW[tid * nk + k];
    } else {                      // bias partials (f32; summed in gemm epilogue)
        kind = 2; orow = job - 102;
        const float* secB;
        switch (orow) {
            case 0:  secB = scalar_b; wblk = 3; break;
            case 1:  secB = bet_b;    wblk = 4; break;
            case 2:  secB = action_b; wblk = 5; break;
            default: secB = blind_b;  wblk = 7; break;
        }
        vsh[tid] = secB[tid];
    }

    const float* Wbase = combine_W + wblk * D;
    float acc = 0.f;

    for (int t = 0; t < 8; ++t) {
        const int k0 = t * 32;
        __syncthreads();
#pragma unroll
        for (int i = 0; i < 8; ++i) {
            const int fidx = tid + i * 256;
            const int dd = fidx >> 3;
            const int kq = (fidx & 7) * 4;
            const float4 w = *(const float4*)(Wbase + (size_t)dd * W8 + k0 + kq);
            float* p = Wl + dd * 33 + kq;
            p[0] = w.x; p[1] = w.y; p[2] = w.z; p[3] = w.w;
        }
        __syncthreads();
        const float* wrow = Wl + tid * 33;
#pragma unroll
        for (int kk = 0; kk < 32; kk += 4) {
            const float4 vv = *(const float4*)(vsh + k0 + kk);
            acc += wrow[kk]     * vv.x + wrow[kk + 1] * vv.y
                 + wrow[kk + 2] * vv.z + wrow[kk + 3] * vv.w;
        }
    }

    ushort* tbT = (ushort*)(ws + TBT_OFF);
    float*  bpl = ws + BPART_OFF;
    if (kind == 0)      tbT[(size_t)tid * KS + orow]      = bf16rne(acc * scale);
    else if (kind == 1) tbT[(size_t)tid * KS + 81 + orow] = bf16rne(acc);
    else                bpl[orow * D + tid] = acc;
}

// -------- GEMM: swapped-operand MFMA, 2 tiles/block, 2n×4m wave shape -------
// R28: wave shape changed from 1n×8m (9 LDS reads / 8 MFMA per kt) to 2n×4m
// (6 reads / 8 MFMA) -> hot-loop ds_read_b128 count 36->24 per wave-tile and
// bank conflicts (685K observed, KS=136 -> 8-way groups) drop ~1/3.
// Everything else identical to R26 (best measured: 28.63us, NT stores).

#define GEMM_THREADS 256

struct Feat {
    int   c[7], ho, ao, no;
    float fs0, fs1, fb[9], fa[8], fl0, fl1, m;
};

__device__ __forceinline__ void preload(
    int q, int tok, int ok,
    const int* __restrict__ cards,  const int* __restrict__ hero,
    const int* __restrict__ acting, const int* __restrict__ nump,
    const float* __restrict__ scalars, const float* __restrict__ blinds,
    const float* __restrict__ bets,    const float* __restrict__ action,
    const float* __restrict__ mask, Feat& f)
{
    if (!ok) { f.m = 0.f; return; }
    if (q == 0) {
        const int* cp = cards + (size_t)tok * 7;
#pragma unroll
        for (int j = 0; j < 7; ++j) f.c[j] = cp[j];
        f.ho = hero[tok]; f.ao = acting[tok]; f.no = nump[tok];
        f.m = mask[tok];
    } else if (q == 1) {
        const float2 s = *(const float2*)(scalars + (size_t)tok * 2);
        f.fs0 = s.x; f.fs1 = s.y;
        const float* fb = bets + (size_t)tok * 9;
#pragma unroll
        for (int k = 0; k < 9; ++k) f.fb[k] = fb[k];
    } else if (q == 2) {
        const float* fa = action + (size_t)tok * 8;
#pragma unroll
        for (int k = 0; k < 8; ++k) f.fa[k] = fa[k];
        const float2 l = *(const float2*)(blinds + (size_t)tok * 2);
        f.fl0 = l.x; f.fl1 = l.y;
    }
}

__device__ __forceinline__ void writeF(int q, int t, int ok, const Feat& f,
                                       ushort* __restrict__ Fl, float* __restrict__ msk)
{
    ushort* Fr = Fl + t * KS;
    if (q == 0) {
        if (ok) {
            int cnt[7];
#pragma unroll
            for (int j = 0; j < 7; ++j) {
                int n = 1;
#pragma unroll
                for (int i = 0; i < 7; ++i)
                    if (i != j) n += (f.c[i] == f.c[j]) ? 1 : 0;
                cnt[j] = n;
            }
#pragma unroll
            for (int j = 0; j < 7; ++j)
                Fr[f.c[j]] = bf16rne((float)cnt[j]);   // exact for cnt<=7
            Fr[53 + f.ho] = 0x3F80;
            Fr[62 + f.ao] = 0x3F80;
            Fr[71 + f.no] = 0x3F80;
        }
        msk[t] = f.m;
    } else if (q == 1 && ok) {
        Fr[81] = bf16rne(f.fs0); Fr[82] = bf16rne(f.fs1);
#pragma unroll
        for (int k = 0; k < 9; ++k) Fr[83 + k] = bf16rne(f.fb[k]);
    } else if (q == 2 && ok) {
#pragma unroll
        for (int k = 0; k < 8; ++k) Fr[92 + k] = bf16rne(f.fa[k]);
        Fr[100] = bf16rne(f.fl0); Fr[101] = bf16rne(f.fl1);
    }
}

__device__ __forceinline__ void mfma_tile(
    const ushort* __restrict__ Tl, const ushort* __restrict__ Fl,
    const float* __restrict__ msk, const float* __restrict__ bsh,
    int tok0, int h, int w, int lr, int lg,
    float* __restrict__ out, int ntok)
{
    const int nbase = (w >> 1) * 2;   // n-tiles {nbase, nbase+1} (16 tokens each)
    const int mbase = (w & 1) * 4;    // m-tiles {mbase..mbase+3} (16 d each)

    f32x4 acc[2][4];
#pragma unroll
    for (int nt = 0; nt < 2; ++nt)
#pragma unroll
        for (int mt = 0; mt < 4; ++mt) acc[nt][mt] = (f32x4){0.f, 0.f, 0.f, 0.f};

#pragma unroll
    for (int kt = 0; kt < 4; ++kt) {
        const short8 b0 = *(const short8*)(Fl + ((nbase + 0) * 16 + lr) * KS + kt * 32 + lg * 8);
        const short8 b1 = *(const short8*)(Fl + ((nbase + 1) * 16 + lr) * KS + kt * 32 + lg * 8);
#pragma unroll
        for (int mt = 0; mt < 4; ++mt) {
            const short8 a = *(const short8*)(Tl + ((mbase + mt) * 16 + lr) * KS + kt * 32 + lg * 8);
            acc[0][mt] = __builtin_amdgcn_mfma_f32_16x16x32_bf16(a, b0, acc[0][mt], 0, 0, 0);
            acc[1][mt] = __builtin_amdgcn_mfma_f32_16x16x32_bf16(a, b1, acc[1][mt], 0, 0, 0);
        }
    }

    // C: m = (mbase+mt)*16 + lg*4 + j (d), n = (nbase+nt)*16 + lr (token)
#pragma unroll
    for (int nt = 0; nt < 2; ++nt) {
        const int trow = (nbase + nt) * 16 + lr;
        const int tok = tok0 + trow;
        if (tok < ntok) {
            const float m = msk[trow];
#pragma unroll
            for (int mt = 0; mt < 4; ++mt) {
                const int c = (mbase + mt) * 16 + lg * 4;
                const float4 bb = *(const float4*)(bsh + c);
                nf4 o;
                o.x = (acc[nt][mt][0] + bb.x) * m;
                o.y = (acc[nt][mt][1] + bb.y) * m;
                o.z = (acc[nt][mt][2] + bb.z) * m;
                o.w = (acc[nt][mt][3] + bb.w) * m;
                __builtin_nontemporal_store(o, (nf4*)(out + (size_t)tok * D + h * 128 + c));
            }
        }
    }
}

__global__ __launch_bounds__(GEMM_THREADS) void gemm_kernel(
    const int* __restrict__ cards,  const int* __restrict__ hero,
    const int* __restrict__ acting, const int* __restrict__ nump,
    const float* __restrict__ scalars, const float* __restrict__ blinds,
    const float* __restrict__ bets,    const float* __restrict__ action,
    const float* __restrict__ mask,    const float* __restrict__ combine_b,
    const float* __restrict__ ws, float* __restrict__ out, int ntok, int ntiles)
{
    __shared__ __align__(16) ushort Tl[128 * KS];  // 34816 B
    __shared__ __align__(16) ushort Fl[64 * KS];   // 17408 B
    __shared__ float msk[64];
    __shared__ float bsh[128];

    const int tid  = threadIdx.x;
    const int h    = blockIdx.x & 1;
    const int tileA = (blockIdx.x >> 1) * 2;
    const int tileB = tileA + 1;
    const int tokA = tileA * 64;
    const int tokB = tileB * 64;

    const int q = tid >> 6;
    const int t = tid & 63;

    // phase 0: issue T-stage + F-zero + bias; preload tile-A features (regs)
    {
        const float4* src = (const float4*)((const ushort*)(ws + TBT_OFF) + (size_t)h * 128 * KS);
        float4* dst = (float4*)Tl;
        for (int i = tid; i < 128 * 17; i += GEMM_THREADS) dst[i] = src[i];
        uint* fz = (uint*)Fl;
        for (int i = tid; i < 64 * KS / 2; i += GEMM_THREADS) fz[i] = 0;
        if (tid < 128) {
            const int c = h * 128 + tid;
            bsh[tid] = combine_b[c]
                + ws[BPART_OFF + 0 * D + c] + ws[BPART_OFF + 1 * D + c]
                + ws[BPART_OFF + 2 * D + c] + ws[BPART_OFF + 3 * D + c];
        }
    }
    Feat fA;
    preload(q, tokA + t, tokA + t < ntok, cards, hero, acting, nump,
            scalars, blinds, bets, action, mask, fA);
    __syncthreads();

    // phase 1: write F(A)
    writeF(q, t, tokA + t < ntok, fA, Fl, msk);
    __syncthreads();

    // phase 2: MFMA + store tile A; preload tile-B features
    const int w  = tid >> 6;
    const int l  = tid & 63;
    const int lr = l & 15;
    const int lg = l >> 4;
    mfma_tile(Tl, Fl, msk, bsh, tokA, h, w, lr, lg, out, ntok);

    const int haveB = (tileB < ntiles);
    Feat fB;
    preload(q, tokB + t, haveB && (tokB + t < ntok), cards, hero, acting, nump,
            scalars, blinds, bets, action, mask, fB);
    __syncthreads();   // all Fl reads of tile A complete

    if (haveB) {
        // phase 3: q0 zeroes its stale tile-A slots, then write F(B)
        if (q == 0 && tokA + t < ntok) {
            ushort* Fr = Fl + t * KS;
#pragma unroll
            for (int j = 0; j < 7; ++j) Fr[fA.c[j]] = 0;
            Fr[53 + fA.ho] = 0; Fr[62 + fA.ao] = 0; Fr[71 + fA.no] = 0;
        }
        if (tokB + t >= ntok) {
            ushort* Fr = Fl + t * KS;
            if (q == 1) { for (int k = 81; k < 92; ++k) Fr[k] = 0; }
            if (q == 2) { for (int k = 92; k < 102; ++k) Fr[k] = 0; }
        }
        writeF(q, t, tokB + t < ntok, fB, Fl, msk);
        __syncthreads();

        // phase 4: MFMA + store tile B
        mfma_tile(Tl, Fl, msk, bsh, tokB, h, w, lr, lg, out, ntok);
    }
}

extern "C" void kernel_launch(void* const* d_in, const int* in_sizes, int n_in,
                              void* d_out, int out_size, void* d_ws, size_t ws_size,
                              hipStream_t stream) {
    const int*   cards    = (const int*)d_in[0];
    const int*   hero     = (const int*)d_in[1];
    const int*   acting   = (const int*)d_in[2];
    const int*   nump     = (const int*)d_in[3];
    const float* scalars  = (const float*)d_in[4];
    const float* blinds   = (const float*)d_in[5];
    const float* bets     = (const float*)d_in[6];
    const float* action   = (const float*)d_in[7];
    const float* mask     = (const float*)d_in[8];
    const float* card_t   = (const float*)d_in[9];
    const float* hero_t   = (const float*)d_in[10];
    const float* act_t    = (const float*)d_in[11];
    const float* nump_t   = (const float*)d_in[12];
    const float* scalar_W = (const float*)d_in[13];
    const float* scalar_b = (const float*)d_in[14];
    const float* blind_W  = (const float*)d_in[15];
    const float* blind_b  = (const float*)d_in[16];
    const float* bet_W    = (const float*)d_in[17];
    const float* bet_b    = (const float*)d_in[18];
    const float* action_W = (const float*)d_in[19];
    const float* action_b = (const float*)d_in[20];
    const float* combine_W= (const float*)d_in[21];
    const float* combine_b= (const float*)d_in[22];

    float* ws  = (float*)d_ws;
    float* out = (float*)d_out;
    const int ntok = in_sizes[1];  // B*S

    const int ntiles = (ntok + 63) / 64;
    const int npairs = (ntiles + 1) / 2;

    hipLaunchKernelGGL(fuse5_kernel, dim3(106), dim3(256), 0, stream,
                       combine_W, card_t, hero_t, act_t, nump_t,
                       scalar_W, scalar_b, blind_W, blind_b, bet_W, bet_b,
                       action_W, action_b, ws);
    hipLaunchKernelGGL(gemm_kernel, dim3(npairs * 2), dim3(GEMM_THREADS), 0, stream,
                       cards, hero, acting, nump, scalars, blinds, bets, action, mask,
                       combine_b, ws, out, ntok, ntiles);
}

// Round 29
// 24.513 us; speedup vs baseline: 1.1905x; 1.1411x over previous
//
#include <hip/hip_runtime.h>

#define D 256
#define W8 2048

// ws float offsets: BPART (4x256 f32) at 0; T^T bf16 [256 d][136 k] at 1024
#define BPART_OFF 0
#define TBT_OFF   1024
#define KS 136     // padded K stride (halfwords); K used = 102 (F zero-covers the rest)

typedef float nf4  __attribute__((ext_vector_type(4)));
typedef float f32x4 __attribute__((ext_vector_type(4)));
typedef short short8 __attribute__((ext_vector_type(8)));   // 8 bf16 = 4 VGPR
typedef short short8a2 __attribute__((ext_vector_type(8), aligned(2)));

__device__ __forceinline__ ushort bf16rne(float v) {
    const unsigned x = __float_as_uint(v);
    return (ushort)((x + 0x7fffu + ((x >> 16) & 1u)) >> 16);
}

// -------- fuse v5 (R17 core) — emits bf16 T^T rows [d][k] + f32 bias partials

__global__ __launch_bounds__(256) void fuse5_kernel(
    const float* __restrict__ combine_W,
    const float* __restrict__ card_t, const float* __restrict__ hero_t,
    const float* __restrict__ act_t,  const float* __restrict__ nump_t,
    const float* __restrict__ scalar_W, const float* __restrict__ scalar_b,
    const float* __restrict__ blind_W,  const float* __restrict__ blind_b,
    const float* __restrict__ bet_W,    const float* __restrict__ bet_b,
    const float* __restrict__ action_W, const float* __restrict__ action_b,
    float* __restrict__ ws)
{
    __shared__ float vsh[D];
    __shared__ float Wl[D * 33];

    const int job = blockIdx.x;   // 0..105
    const int tid = threadIdx.x;

    int wblk;
    float scale = 1.0f;
    int kind, orow;

    if (job < 81) {               // T rows k=0..80 (card pre-scaled 1/7)
        kind = 0; orow = job;
        const float* src;
        if (job < 53)      { src = card_t + job * D;        wblk = 0; scale = 1.0f / 7.0f; }
        else if (job < 62) { src = hero_t + (job - 53) * D; wblk = 1; }
        else if (job < 71) { src = act_t  + (job - 62) * D; wblk = 2; }
        else               { src = nump_t + (job - 71) * D; wblk = 6; }
        vsh[tid] = src[tid];
    } else if (job < 102) {       // T rows k=81..101 (section weight columns)
        kind = 1; orow = job - 81;
        const float* secW; int nk, k;
        if (orow < 2)       { secW = scalar_W; nk = 2; k = orow;      wblk = 3; }
        else if (orow < 11) { secW = bet_W;    nk = 9; k = orow - 2;  wblk = 4; }
        else if (orow < 19) { secW = action_W; nk = 8; k = orow - 11; wblk = 5; }
        else                { secW = blind_W;  nk = 2; k = orow - 19; wblk = 7; }
        vsh[tid] = secW[tid * nk + k];
    } else {                      // bias partials (f32; summed in gemm epilogue)
        kind = 2; orow = job - 102;
        const float* secB;
        switch (orow) {
            case 0:  secB = scalar_b; wblk = 3; break;
            case 1:  secB = bet_b;    wblk = 4; break;
            case 2:  secB = action_b; wblk = 5; break;
            default: secB = blind_b;  wblk = 7; break;
        }
        vsh[tid] = secB[tid];
    }

    const float* Wbase = combine_W + wblk * D;
    float acc = 0.f;

    for (int t = 0; t < 8; ++t) {
        const int k0 = t * 32;
        __syncthreads();
#pragma unroll
        for (int i = 0; i < 8; ++i) {
            const int fidx = tid + i * 256;
            const int dd = fidx >> 3;
            const int kq = (fidx & 7) * 4;
            const float4 w = *(const float4*)(Wbase + (size_t)dd * W8 + k0 + kq);
            float* p = Wl + dd * 33 + kq;
            p[0] = w.x; p[1] = w.y; p[2] = w.z; p[3] = w.w;
        }
        __syncthreads();
        const float* wrow = Wl + tid * 33;
#pragma unroll
        for (int kk = 0; kk < 32; kk += 4) {
            const float4 vv = *(const float4*)(vsh + k0 + kk);
            acc += wrow[kk]     * vv.x + wrow[kk + 1] * vv.y
                 + wrow[kk + 2] * vv.z + wrow[kk + 3] * vv.w;
        }
    }

    ushort* tbT = (ushort*)(ws + TBT_OFF);
    float*  bpl = ws + BPART_OFF;
    if (kind == 0)      tbT[(size_t)tid * KS + orow]      = bf16rne(acc * scale);
    else if (kind == 1) tbT[(size_t)tid * KS + 81 + orow] = bf16rne(acc);
    else                bpl[orow * D + tid] = acc;
}

// -------- GEMM: a-fragments DIRECT from L1/L2 (no Tl), 2 tiles/block --------
// R29 single-variable experiment: delete the 34.8 KB Tl stage. T is only
// 69.6 KB total and shared by every block -> L1/L2-hot after first touch.
// Removes the per-block serial T-stage+drain phase and drops LDS 53->18 KB
// (blocks/CU 2 -> 4+, resident waves 2x). MFMA layout/fragments unchanged.

#define GEMM_THREADS 256

struct Feat {
    int   c[7], ho, ao, no;
    float fs0, fs1, fb[9], fa[8], fl0, fl1, m;
};

__device__ __forceinline__ void preload(
    int q, int tok, int ok,
    const int* __restrict__ cards,  const int* __restrict__ hero,
    const int* __restrict__ acting, const int* __restrict__ nump,
    const float* __restrict__ scalars, const float* __restrict__ blinds,
    const float* __restrict__ bets,    const float* __restrict__ action,
    const float* __restrict__ mask, Feat& f)
{
    if (!ok) { f.m = 0.f; return; }
    if (q == 0) {
        const int* cp = cards + (size_t)tok * 7;
#pragma unroll
        for (int j = 0; j < 7; ++j) f.c[j] = cp[j];
        f.ho = hero[tok]; f.ao = acting[tok]; f.no = nump[tok];
        f.m = mask[tok];
    } else if (q == 1) {
        const float2 s = *(const float2*)(scalars + (size_t)tok * 2);
        f.fs0 = s.x; f.fs1 = s.y;
        const float* fb = bets + (size_t)tok * 9;
#pragma unroll
        for (int k = 0; k < 9; ++k) f.fb[k] = fb[k];
    } else if (q == 2) {
        const float* fa = action + (size_t)tok * 8;
#pragma unroll
        for (int k = 0; k < 8; ++k) f.fa[k] = fa[k];
        const float2 l = *(const float2*)(blinds + (size_t)tok * 2);
        f.fl0 = l.x; f.fl1 = l.y;
    }
}

__device__ __forceinline__ void writeF(int q, int t, int ok, const Feat& f,
                                       ushort* __restrict__ Fl, float* __restrict__ msk)
{
    ushort* Fr = Fl + t * KS;
    if (q == 0) {
        if (ok) {
            int cnt[7];
#pragma unroll
            for (int j = 0; j < 7; ++j) {
                int n = 1;
#pragma unroll
                for (int i = 0; i < 7; ++i)
                    if (i != j) n += (f.c[i] == f.c[j]) ? 1 : 0;
                cnt[j] = n;
            }
#pragma unroll
            for (int j = 0; j < 7; ++j)
                Fr[f.c[j]] = bf16rne((float)cnt[j]);   // exact for cnt<=7
            Fr[53 + f.ho] = 0x3F80;
            Fr[62 + f.ao] = 0x3F80;
            Fr[71 + f.no] = 0x3F80;
        }
        msk[t] = f.m;
    } else if (q == 1 && ok) {
        Fr[81] = bf16rne(f.fs0); Fr[82] = bf16rne(f.fs1);
#pragma unroll
        for (int k = 0; k < 9; ++k) Fr[83 + k] = bf16rne(f.fb[k]);
    } else if (q == 2 && ok) {
#pragma unroll
        for (int k = 0; k < 8; ++k) Fr[92 + k] = bf16rne(f.fa[k]);
        Fr[100] = bf16rne(f.fl0); Fr[101] = bf16rne(f.fl1);
    }
}

__device__ __forceinline__ void mfma_tile(
    const ushort* __restrict__ Tg,   // global T^T half base (L1/L2-hot)
    const ushort* __restrict__ Fl,
    const float* __restrict__ msk, const float* __restrict__ bsh,
    int tok0, int h, int w, int lr, int lg,
    float* __restrict__ out, int ntok)
{
    const int nbase = (w >> 1) * 2;   // n-tiles {nbase, nbase+1} (16 tokens each)
    const int mbase = (w & 1) * 4;    // m-tiles {mbase..mbase+3} (16 d each)

    f32x4 acc[2][4];
#pragma unroll
    for (int nt = 0; nt < 2; ++nt)
#pragma unroll
        for (int mt = 0; mt < 4; ++mt) acc[nt][mt] = (f32x4){0.f, 0.f, 0.f, 0.f};

#pragma unroll
    for (int kt = 0; kt < 4; ++kt) {
        const short8 b0 = *(const short8*)(Fl + ((nbase + 0) * 16 + lr) * KS + kt * 32 + lg * 8);
        const short8 b1 = *(const short8*)(Fl + ((nbase + 1) * 16 + lr) * KS + kt * 32 + lg * 8);
#pragma unroll
        for (int mt = 0; mt < 4; ++mt) {
            const short8 a = *(const short8a2*)(Tg + (size_t)((mbase + mt) * 16 + lr) * KS + kt * 32 + lg * 8);
            acc[0][mt] = __builtin_amdgcn_mfma_f32_16x16x32_bf16(a, b0, acc[0][mt], 0, 0, 0);
            acc[1][mt] = __builtin_amdgcn_mfma_f32_16x16x32_bf16(a, b1, acc[1][mt], 0, 0, 0);
        }
    }

    // C: m = (mbase+mt)*16 + lg*4 + j (d), n = (nbase+nt)*16 + lr (token)
#pragma unroll
    for (int nt = 0; nt < 2; ++nt) {
        const int trow = (nbase + nt) * 16 + lr;
        const int tok = tok0 + trow;
        if (tok < ntok) {
            const float m = msk[trow];
#pragma unroll
            for (int mt = 0; mt < 4; ++mt) {
                const int c = (mbase + mt) * 16 + lg * 4;
                const float4 bb = *(const float4*)(bsh + c);
                nf4 o;
                o.x = (acc[nt][mt][0] + bb.x) * m;
                o.y = (acc[nt][mt][1] + bb.y) * m;
                o.z = (acc[nt][mt][2] + bb.z) * m;
                o.w = (acc[nt][mt][3] + bb.w) * m;
                __builtin_nontemporal_store(o, (nf4*)(out + (size_t)tok * D + h * 128 + c));
            }
        }
    }
}

__global__ __launch_bounds__(GEMM_THREADS) void gemm_kernel(
    const int* __restrict__ cards,  const int* __restrict__ hero,
    const int* __restrict__ acting, const int* __restrict__ nump,
    const float* __restrict__ scalars, const float* __restrict__ blinds,
    const float* __restrict__ bets,    const float* __restrict__ action,
    const float* __restrict__ mask,    const float* __restrict__ combine_b,
    const float* __restrict__ ws, float* __restrict__ out, int ntok, int ntiles)
{
    __shared__ __align__(16) ushort Fl[64 * KS];   // 17408 B (no Tl — R29)
    __shared__ float msk[64];
    __shared__ float bsh[128];

    const int tid  = threadIdx.x;
    const int h    = blockIdx.x & 1;
    const int tileA = (blockIdx.x >> 1) * 2;
    const int tileB = tileA + 1;
    const int tokA = tileA * 64;
    const int tokB = tileB * 64;

    const int q = tid >> 6;
    const int t = tid & 63;

    const ushort* Tg = (const ushort*)(ws + TBT_OFF) + (size_t)h * 128 * KS;

    // phase 0: zero F + bias; preload tile-A features (regs)
    {
        uint* fz = (uint*)Fl;
        for (int i = tid; i < 64 * KS / 2; i += GEMM_THREADS) fz[i] = 0;
        if (tid < 128) {
            const int c = h * 128 + tid;
            bsh[tid] = combine_b[c]
                + ws[BPART_OFF + 0 * D + c] + ws[BPART_OFF + 1 * D + c]
                + ws[BPART_OFF + 2 * D + c] + ws[BPART_OFF + 3 * D + c];
        }
    }
    Feat fA;
    preload(q, tokA + t, tokA + t < ntok, cards, hero, acting, nump,
            scalars, blinds, bets, action, mask, fA);
    __syncthreads();

    // phase 1: write F(A)
    writeF(q, t, tokA + t < ntok, fA, Fl, msk);
    __syncthreads();

    // phase 2: MFMA + store tile A; preload tile-B features
    const int w  = tid >> 6;
    const int l  = tid & 63;
    const int lr = l & 15;
    const int lg = l >> 4;
    mfma_tile(Tg, Fl, msk, bsh, tokA, h, w, lr, lg, out, ntok);

    const int haveB = (tileB < ntiles);
    Feat fB;
    preload(q, tokB + t, haveB && (tokB + t < ntok), cards, hero, acting, nump,
            scalars, blinds, bets, action, mask, fB);
    __syncthreads();   // all Fl reads of tile A complete

    if (haveB) {
        // phase 3: q0 zeroes its stale tile-A slots, then write F(B)
        if (q == 0 && tokA + t < ntok) {
            ushort* Fr = Fl + t * KS;
#pragma unroll
            for (int j = 0; j < 7; ++j) Fr[fA.c[j]] = 0;
            Fr[53 + fA.ho] = 0; Fr[62 + fA.ao] = 0; Fr[71 + fA.no] = 0;
        }
        if (tokB + t >= ntok) {
            ushort* Fr = Fl + t * KS;
            if (q == 1) { for (int k = 81; k < 92; ++k) Fr[k] = 0; }
            if (q == 2) { for (int k = 92; k < 102; ++k) Fr[k] = 0; }
        }
        writeF(q, t, tokB + t < ntok, fB, Fl, msk);
        __syncthreads();

        // phase 4: MFMA + store tile B
        mfma_tile(Tg, Fl, msk, bsh, tokB, h, w, lr, lg, out, ntok);
    }
}

extern "C" void kernel_launch(void* const* d_in, const int* in_sizes, int n_in,
                              void* d_out, int out_size, void* d_ws, size_t ws_size,
                              hipStream_t stream) {
    const int*   cards    = (const int*)d_in[0];
    const int*   hero     = (const int*)d_in[1];
    const int*   acting   = (const int*)d_in[2];
    const int*   nump     = (const int*)d_in[3];
    const float* scalars  = (const float*)d_in[4];
    const float* blinds   = (const float*)d_in[5];
    const float* bets     = (const float*)d_in[6];
    const float* action   = (const float*)d_in[7];
    const float* mask     = (const float*)d_in[8];
    const float* card_t   = (const float*)d_in[9];
    const float* hero_t   = (const float*)d_in[10];
    const float* act_t    = (const float*)d_in[11];
    const float* nump_t   = (const float*)d_in[12];
    const float* scalar_W = (const float*)d_in[13];
    const float* scalar_b = (const float*)d_in[14];
    const float* blind_W  = (const float*)d_in[15];
    const float* blind_b  = (const float*)d_in[16];
    const float* bet_W    = (const float*)d_in[17];
    const float* bet_b    = (const float*)d_in[18];
    const float* action_W = (const float*)d_in[19];
    const float* action_b = (const float*)d_in[20];
    const float* combine_W= (const float*)d_in[21];
    const float* combine_b= (const float*)d_in[22];

    float* ws  = (float*)d_ws;
    float* out = (float*)d_out;
    const int ntok = in_sizes[1];  // B*S

    const int ntiles = (ntok + 63) / 64;
    const int npairs = (ntiles + 1) / 2;

    hipLaunchKernelGGL(fuse5_kernel, dim3(106), dim3(256), 0, stream,
                       combine_W, card_t, hero_t, act_t, nump_t,
                       scalar_W, scalar_b, blind_W, blind_b, bet_W, bet_b,
                       action_W, action_b, ws);
    hipLaunchKernelGGL(gemm_kernel, dim3(npairs * 2), dim3(GEMM_THREADS), 0, stream,
                       cards, hero, acting, nump, scalars, blinds, bets, action, mask,
                       combine_b, ws, out, ntok, ntiles);
}